// Round 2
// baseline (443.882 us; speedup 1.0000x reference)
//
#include <hip/hip_runtime.h>
#include <hip/hip_bf16.h>

typedef __bf16 bf16x8 __attribute__((ext_vector_type(8)));
typedef float  f32x4  __attribute__((ext_vector_type(4)));

#define BM 128
#define BN 128
#define BK 32

// float -> bf16 round-to-nearest-even (finite inputs)
__device__ __forceinline__ unsigned short f2bf(float f) {
    union { float f; unsigned int u; } v; v.f = f;
    unsigned int r = v.u + 0x7FFFu + ((v.u >> 16) & 1u);
    return (unsigned short)(r >> 16);
}

__device__ __forceinline__ void async16(const unsigned short* g, unsigned short* l) {
    __builtin_amdgcn_global_load_lds(
        (const __attribute__((address_space(1))) unsigned int*)g,
        (__attribute__((address_space(3))) unsigned int*)l,
        16, 0, 0);
}

// ---------------------------------------------------------------------------
// Transpose + cast: Xt[n][m] = (bf16) X[m][n]
// ---------------------------------------------------------------------------
__global__ __launch_bounds__(256) void transpose_to_bf16(
    const float* __restrict__ X, unsigned short* __restrict__ Xt, int Mr, int Nc)
{
    __shared__ float tile[32][33];
    const int bx = blockIdx.x * 32;          // col base in X
    const int by = blockIdx.y * 32;          // row base in X
    const int tx = threadIdx.x & 31;
    const int ty = threadIdx.x >> 5;         // 0..7
#pragma unroll
    for (int j = 0; j < 4; ++j)
        tile[ty + j * 8][tx] = X[(size_t)(by + ty + j * 8) * Nc + bx + tx];
    __syncthreads();
#pragma unroll
    for (int j = 0; j < 4; ++j)
        Xt[(size_t)(bx + ty + j * 8) * Mr + by + tx] = f2bf(tile[tx][ty + j * 8]);
}

// ---------------------------------------------------------------------------
// Generate transform matrix, 4 elems/thread:
//   out[u][k] = sin(pi*k*(2u+1)/(2*Nsz))   if doSin
//   out[u][k] = cos(pi*k*(2u+1)/(2*Nsz))   else
// Exact integer reduction: t = k*(2u+1) mod 4*Nsz, angle = t * pi/(2*Nsz).
// ---------------------------------------------------------------------------
__global__ __launch_bounds__(256) void gen_mat(
    unsigned short* __restrict__ out, int Nsz, int lg, int doSin)
{
    const int flat = (int)(((size_t)blockIdx.x * 256 + threadIdx.x) * 4);
    const int u  = flat >> lg;
    const int k0 = flat & (Nsz - 1);
    const unsigned int step = 2u * (unsigned int)u + 1u;
    const unsigned int mask = 4u * (unsigned int)Nsz - 1u;
    const float scale = 3.14159265358979323846f / (2.0f * (float)Nsz);
    unsigned short o[4];
#pragma unroll
    for (int j = 0; j < 4; ++j) {
        unsigned int p = ((unsigned int)(k0 + j) * step) & mask;
        float ang = (float)p * scale;
        float v = doSin ? __sinf(ang) : __cosf(ang);
        o[j] = f2bf(v);
    }
    uint2 pack;
    pack.x = (unsigned int)o[0] | ((unsigned int)o[1] << 16);
    pack.y = (unsigned int)o[2] | ((unsigned int)o[3] << 16);
    *reinterpret_cast<uint2*>(out + flat) = pack;
}

// ---------------------------------------------------------------------------
// BT-layout bf16 GEMM (m97 structure): C[i][j] = sum_k P[i][k] * Q[j][k]
// P: [Mr][K] bf16 row-major, Q: [Nc][K] bf16 row-major, C: [Mr][Nc] (OutT)
// 128x128 tile, BK=32, 4 waves (2x2), 16x16x32 MFMA, global_load_lds w=16.
// ---------------------------------------------------------------------------
__device__ __forceinline__ void store_out(float* C, size_t idx, float v) { C[idx] = v; }
__device__ __forceinline__ void store_out(unsigned short* C, size_t idx, float v) { C[idx] = f2bf(v); }

template <typename OutT>
__global__ __launch_bounds__(256) void gemm_bt(
    const unsigned short* __restrict__ P,
    const unsigned short* __restrict__ Q,
    OutT* __restrict__ C,
    int Mr, int Nc, int K)
{
    __shared__ __align__(16) unsigned short ldsA[BM * BK];
    __shared__ __align__(16) unsigned short ldsB[BN * BK];

    const int tid  = threadIdx.x;
    const int lane = tid & 63;
    const int w    = tid >> 6;      // 0..3
    const int wr   = w >> 1;        // 0..1
    const int wc   = w & 1;         // 0..1
    const int brow = blockIdx.y * BM;
    const int bcol = blockIdx.x * BN;

    const int lr = lane & 15;       // fragment row
    const int lk = lane >> 4;       // k-group (8 elems each)

    f32x4 acc[4][4] = {};

    for (int k0 = 0; k0 < K; k0 += BK) {
        // stage A tile [BM][BK] and B tile [BN][BK]: 512 chunks of 16B each
#pragma unroll
        for (int i = 0; i < 2; ++i) {
            const int c   = i * 256 + w * 64 + lane;   // chunk id
            const int row = c >> 2;
            const int ko  = (c & 3) << 3;              // bf16 offset in row
            const int lbase = (i * 256 + w * 64) * 8;  // ushort idx (wave-uniform)
            async16(P + (size_t)(brow + row) * K + k0 + ko, &ldsA[lbase]);
            async16(Q + (size_t)(bcol + row) * K + k0 + ko, &ldsB[lbase]);
        }
        __syncthreads();

        bf16x8 af[4], bfr[4];
#pragma unroll
        for (int m = 0; m < 4; ++m)
            af[m] = *(const bf16x8*)&ldsA[(wr * 64 + m * 16 + lr) * BK + lk * 8];
#pragma unroll
        for (int n = 0; n < 4; ++n)
            bfr[n] = *(const bf16x8*)&ldsB[(wc * 64 + n * 16 + lr) * BK + lk * 8];

#pragma unroll
        for (int m = 0; m < 4; ++m)
#pragma unroll
            for (int n = 0; n < 4; ++n)
                acc[m][n] = __builtin_amdgcn_mfma_f32_16x16x32_bf16(af[m], bfr[n], acc[m][n], 0, 0, 0);
        __syncthreads();
    }

    // epilogue: C/D layout col=lane&15, row=(lane>>4)*4+r
    const int r0 = brow + wr * 64 + (lane >> 4) * 4;
    const int c0 = bcol + wc * 64 + (lane & 15);
#pragma unroll
    for (int m = 0; m < 4; ++m)
#pragma unroll
        for (int n = 0; n < 4; ++n)
#pragma unroll
            for (int r = 0; r < 4; ++r)
                store_out(C, (size_t)(r0 + m * 16 + r) * Nc + (c0 + n * 16), acc[m][n][r]);
}

// ---------------------------------------------------------------------------
// launch: Y = A X B^T  via  Xt = X^T;  T = A (.) Xt;  Y = T (.) B
// where (.) is the BT-layout GEMM above.
// ---------------------------------------------------------------------------
extern "C" void kernel_launch(void* const* d_in, const int* in_sizes, int n_in,
                              void* d_out, int out_size, void* d_ws, size_t ws_size,
                              hipStream_t stream) {
    const float* X = (const float*)d_in[0];
    const int Mr = in_sizes[1] / 2;   // 4096
    const int Nc = in_sizes[2] / 2;   // 4096
    const int lgM = 31 - __builtin_clz((unsigned)Mr);
    const int lgN = 31 - __builtin_clz((unsigned)Nc);

    unsigned short* Xt   = (unsigned short*)d_ws;              // [Nc][Mr]
    unsigned short* Wmat = Xt + (size_t)Nc * Mr;               // [4096][4096] (A then B)
    unsigned short* Tmat = Wmat + (size_t)Mr * Mr;             // [Mr][Nc]

    // 1) Xt = transpose(X) in bf16
    transpose_to_bf16<<<dim3(Nc / 32, Mr / 32), 256, 0, stream>>>(X, Xt, Mr, Nc);
    // 2) A = sin matrix (IDXST over M)
    gen_mat<<<(Mr * Mr / 4) / 256, 256, 0, stream>>>(Wmat, Mr, lgM, 1);
    // 3) T[u][n] = sum_k A[u][k] * Xt[n][k]
    gemm_bt<unsigned short><<<dim3(Nc / BN, Mr / BM), 256, 0, stream>>>(Wmat, Xt, Tmat, Mr, Nc, Mr);
    // 4) B = cos matrix (IDCT over N), reuse Wmat
    gen_mat<<<(Nc * Nc / 4) / 256, 256, 0, stream>>>(Wmat, Nc, lgN, 0);
    // 5) Y[u][v] = sum_j T[u][j] * B[v][j]  -> fp32 d_out
    gemm_bt<float><<<dim3(Nc / BN, Mr / BM), 256, 0, stream>>>(Tmat, Wmat, (float*)d_out, Mr, Nc, Nc);
}

// Round 5
// 284.335 us; speedup vs baseline: 1.5611x; 1.5611x over previous
//
#include <hip/hip_runtime.h>
#include <hip/hip_bf16.h>

typedef __bf16 bf16x8 __attribute__((ext_vector_type(8)));
typedef float  f32x4  __attribute__((ext_vector_type(4)));

// float -> bf16 round-to-nearest-even (finite inputs)
__device__ __forceinline__ unsigned short f2bf(float f) {
    union { float f; unsigned int u; } v; v.f = f;
    unsigned int r = v.u + 0x7FFFu + ((v.u >> 16) & 1u);
    return (unsigned short)(r >> 16);
}

__device__ __forceinline__ void async16(const unsigned short* g, unsigned short* l) {
    __builtin_amdgcn_global_load_lds(
        (const __attribute__((address_space(1))) unsigned int*)g,
        (__attribute__((address_space(3))) unsigned int*)l,
        16, 0, 0);
}

// ---------------------------------------------------------------------------
// Transpose + cast: Xt[n][m] = (bf16) X[m][n]
// ---------------------------------------------------------------------------
__global__ __launch_bounds__(256) void transpose_to_bf16(
    const float* __restrict__ X, unsigned short* __restrict__ Xt, int Mr, int Nc)
{
    __shared__ float tile[32][33];
    const int bx = blockIdx.x * 32;
    const int by = blockIdx.y * 32;
    const int tx = threadIdx.x & 31;
    const int ty = threadIdx.x >> 5;
#pragma unroll
    for (int j = 0; j < 4; ++j)
        tile[ty + j * 8][tx] = X[(size_t)(by + ty + j * 8) * Nc + bx + tx];
    __syncthreads();
#pragma unroll
    for (int j = 0; j < 4; ++j)
        Xt[(size_t)(bx + ty + j * 8) * Mr + by + tx] = f2bf(tile[tx][ty + j * 8]);
}

// ---------------------------------------------------------------------------
// Generate transform matrix (bf16), exact integer angle reduction mod 4N.
// ---------------------------------------------------------------------------
__global__ __launch_bounds__(256) void gen_mat(
    unsigned short* __restrict__ out, int Nsz, int lg, int doSin)
{
    const int flat = (int)(((size_t)blockIdx.x * 256 + threadIdx.x) * 4);
    const int u  = flat >> lg;
    const int k0 = flat & (Nsz - 1);
    const unsigned int step = 2u * (unsigned int)u + 1u;
    const unsigned int mask = 4u * (unsigned int)Nsz - 1u;
    const float scale = 3.14159265358979323846f / (2.0f * (float)Nsz);
    unsigned short o[4];
#pragma unroll
    for (int j = 0; j < 4; ++j) {
        unsigned int p = ((unsigned int)(k0 + j) * step) & mask;
        float ang = (float)p * scale;
        float v = doSin ? __sinf(ang) : __cosf(ang);
        o[j] = f2bf(v);
    }
    uint2 pack;
    pack.x = (unsigned int)o[0] | ((unsigned int)o[1] << 16);
    pack.y = (unsigned int)o[2] | ((unsigned int)o[3] << 16);
    *reinterpret_cast<uint2*>(out + flat) = pack;
}

// ---------------------------------------------------------------------------
// 256x256 8-phase BT-layout bf16 GEMM:  C[i][j] = sum_k P[i][k] * Q[j][k]
// BK=64, 8 waves (2Mx4N), per-wave 128x64 C, LDS 128 KiB double-buffered.
// T2 16B-slot XOR swizzle (source-side), counted vmcnt(4), setprio MFMA.
// ---------------------------------------------------------------------------
__device__ __forceinline__ void store_out(float* C, size_t idx, float v) { C[idx] = v; }
__device__ __forceinline__ void store_out(unsigned short* C, size_t idx, float v) { C[idx] = f2bf(v); }

#define BARRIER __builtin_amdgcn_s_barrier()
#define LGKM0 do { asm volatile("s_waitcnt lgkmcnt(0)" ::: "memory"); \
                   __builtin_amdgcn_sched_barrier(0); } while (0)
#define PRIO1 __builtin_amdgcn_s_setprio(1)
#define PRIO0 __builtin_amdgcn_s_setprio(0)

// stage one half-tile slice: half h (0/1 = rows 0-127 / 128-255), L (0/1 = rows 0-63/64-127 of half)
#define STG_A(buf, h, L, kt) async16(pA + (size_t)((h) * 128 + (L) * 64) * K + (size_t)(kt) * 64, \
                                     ldsA + ((buf) << 14) + ((h) << 13) + ((L) << 12) + ldst)
#define STG_B(buf, h, L, kt) async16(pB + (size_t)((h) * 128 + (L) * 64) * K + (size_t)(kt) * 64, \
                                     ldsB + ((buf) << 14) + ((h) << 13) + ((L) << 12) + ldst)

#define LDA(buf, g) do { _Pragma("unroll") for (int mm = 0; mm < 4; ++mm) { \
    af[mm][0] = *(const bf16x8*)&ldsA[((buf) << 14) + aRow + ((g) * 4 + mm) * 1024 + sl0]; \
    af[mm][1] = *(const bf16x8*)&ldsA[((buf) << 14) + aRow + ((g) * 4 + mm) * 1024 + sl1]; } } while (0)

#define LDB(buf, p) do { _Pragma("unroll") for (int nn = 0; nn < 2; ++nn) { \
    bfr[(p) * 2 + nn][0] = *(const bf16x8*)&ldsB[((buf) << 14) + bRow + (((p) * 2 + nn)) * 1024 + sl0]; \
    bfr[(p) * 2 + nn][1] = *(const bf16x8*)&ldsB[((buf) << 14) + bRow + (((p) * 2 + nn)) * 1024 + sl1]; } } while (0)

#define MFMA_Q(g, p) do { _Pragma("unroll") for (int mm = 0; mm < 4; ++mm) \
    _Pragma("unroll") for (int nn = 0; nn < 2; ++nn) { \
    acc[(g) * 4 + mm][(p) * 2 + nn] = __builtin_amdgcn_mfma_f32_16x16x32_bf16( \
        af[mm][0], bfr[(p) * 2 + nn][0], acc[(g) * 4 + mm][(p) * 2 + nn], 0, 0, 0); \
    acc[(g) * 4 + mm][(p) * 2 + nn] = __builtin_amdgcn_mfma_f32_16x16x32_bf16( \
        af[mm][1], bfr[(p) * 2 + nn][1], acc[(g) * 4 + mm][(p) * 2 + nn], 0, 0, 0); } } while (0)

// One K-tile (4 phases). buf = current, nbuf = other. Stages A(t+1)->nbuf at P1/P2,
// B(t+2)->buf at P3/P4 (B region of buf is dead after P2). vmN: 4 steady, 0 at tail.
#define TILE(buf, nbuf, kt, doSA, doSB, vmN) do { \
    /* P1 */ LDA(buf, 0); LDB(buf, 0); \
    if (doSA) { STG_A(nbuf, 0, 0, (kt) + 1); STG_A(nbuf, 0, 1, (kt) + 1); } \
    BARRIER; LGKM0; PRIO1; MFMA_Q(0, 0); PRIO0; BARRIER; \
    /* P2 */ LDB(buf, 1); \
    if (doSA) { STG_A(nbuf, 1, 0, (kt) + 1); STG_A(nbuf, 1, 1, (kt) + 1); } \
    BARRIER; LGKM0; PRIO1; MFMA_Q(0, 1); PRIO0; BARRIER; \
    /* P3 */ LDA(buf, 1); \
    if (doSB) { STG_B(buf, 0, 0, (kt) + 2); STG_B(buf, 0, 1, (kt) + 2); } \
    BARRIER; LGKM0; PRIO1; MFMA_Q(1, 0); PRIO0; BARRIER; \
    /* P4 */ \
    if (doSB) { STG_B(buf, 1, 0, (kt) + 2); STG_B(buf, 1, 1, (kt) + 2); } \
    BARRIER; PRIO1; MFMA_Q(1, 1); PRIO0; \
    asm volatile("s_waitcnt vmcnt(" #vmN ")" ::: "memory"); \
    BARRIER; } while (0)

template <typename OutT>
__global__ __launch_bounds__(512, 2) void gemm_bt8(
    const unsigned short* __restrict__ P,
    const unsigned short* __restrict__ Q,
    OutT* __restrict__ C,
    int Mr, int Nc, int K)
{
    __shared__ __align__(16) unsigned short ldsA[2 * 256 * 64];
    __shared__ __align__(16) unsigned short ldsB[2 * 256 * 64];

    const int tid  = threadIdx.x;
    const int lane = tid & 63;
    const int w    = tid >> 6;       // 0..7
    const int wm   = w >> 2;         // 0..1  (M half)
    const int wn   = w & 3;          // 0..3  (N quarter)

    // XCD-bijective block swizzle (gridDim.x % 8 == 0)
    const int nbx = Nc >> 8;
    const int bid = blockIdx.x;
    const int wg  = (bid & 7) * (gridDim.x >> 3) + (bid >> 3);
    const int brow = (wg / nbx) << 8;
    const int bcol = (wg % nbx) << 8;

    // staging constants: chunk c = L*512 + tid; row = c>>3 (within half), slot = c&7
    const int srow = tid >> 3;                        // 0..63 (L adds 64)
    const int slot = tid & 7;
    const int sxor = ((slot ^ (srow & 7)) << 3);      // pre-swizzled ushort col offset
    const unsigned short* pA = P + (size_t)(brow + srow) * K + sxor;
    const unsigned short* pB = Q + (size_t)(bcol + srow) * K + sxor;
    const int ldst = w << 9;                          // wave-uniform LDS dest (+lane*16B by HW)

    // fragment-read constants (read-side swizzle matches source-side XOR)
    const int lr = lane & 15, lk = lane >> 4, sx = lr & 7;
    const int sl0 = ((lk) ^ sx) << 3;                 // k-step 0 slot
    const int sl1 = ((4 + lk) ^ sx) << 3;             // k-step 1 slot
    const int aRow = (wm * 128 + lr) * 64;
    const int bRow = (wn * 64 + lr) * 64;

    bf16x8 af[4][2], bfr[4][2];
    f32x4 acc[8][4] = {};

    const int nt = K >> 6;   // K-tiles of 64

    // prologue: A(0),B(0) -> buf0; B(1) -> buf1. Keep B(1) in flight.
    STG_A(0, 0, 0, 0); STG_A(0, 0, 1, 0); STG_A(0, 1, 0, 0); STG_A(0, 1, 1, 0);
    STG_B(0, 0, 0, 0); STG_B(0, 0, 1, 0); STG_B(0, 1, 0, 0); STG_B(0, 1, 1, 0);
    STG_B(1, 0, 0, 1); STG_B(1, 0, 1, 1); STG_B(1, 1, 0, 1); STG_B(1, 1, 1, 1);
    asm volatile("s_waitcnt vmcnt(4)" ::: "memory");
    BARRIER;

    for (int i = 0; i < (nt >> 1) - 1; ++i) {
        const int t0 = 2 * i;
        TILE(0, 1, t0,     1, 1, 4);
        TILE(1, 0, t0 + 1, 1, 1, 4);
    }
    TILE(0, 1, nt - 2, 1, 0, 0);
    TILE(1, 0, nt - 1, 0, 0, 0);

    // epilogue: C/D layout col=lane&15, row=(lane>>4)*4+r
    const int r0 = brow + wm * 128 + (lane >> 4) * 4;
    const int c0 = bcol + wn * 64 + (lane & 15);
#pragma unroll
    for (int m = 0; m < 8; ++m)
#pragma unroll
        for (int n = 0; n < 4; ++n)
#pragma unroll
            for (int r = 0; r < 4; ++r)
                store_out(C, (size_t)(r0 + m * 16 + r) * Nc + (c0 + n * 16), acc[m][n][r]);
}

// ---------------------------------------------------------------------------
// launch: Y = A X B^T  via  Xt = X^T;  T = A (.) Xt;  Y = T (.) B
// ---------------------------------------------------------------------------
extern "C" void kernel_launch(void* const* d_in, const int* in_sizes, int n_in,
                              void* d_out, int out_size, void* d_ws, size_t ws_size,
                              hipStream_t stream) {
    const float* X = (const float*)d_in[0];
    const int Mr = in_sizes[1] / 2;   // 4096
    const int Nc = in_sizes[2] / 2;   // 4096
    const int lgM = 31 - __builtin_clz((unsigned)Mr);
    const int lgN = 31 - __builtin_clz((unsigned)Nc);

    unsigned short* Xt   = (unsigned short*)d_ws;              // [Nc][Mr]
    unsigned short* Wmat = Xt + (size_t)Nc * Mr;               // [4096][4096] (A then B)
    unsigned short* Tmat = Wmat + (size_t)Mr * Mr;             // [Mr][Nc]

    transpose_to_bf16<<<dim3(Nc / 32, Mr / 32), 256, 0, stream>>>(X, Xt, Mr, Nc);
    gen_mat<<<(Mr * Mr / 4) / 256, 256, 0, stream>>>(Wmat, Mr, lgM, 1);

    const int nblk = (Mr / 256) * (Nc / 256);
    gemm_bt8<unsigned short><<<nblk, 512, 0, stream>>>(Wmat, Xt, Tmat, Mr, Nc, Mr);

    gen_mat<<<(Nc * Nc / 4) / 256, 256, 0, stream>>>(Wmat, Nc, lgN, 0);
    gemm_bt8<float><<<nblk, 512, 0, stream>>>(Tmat, Wmat, (float*)d_out, Mr, Nc, Nc);
}

// Round 6
// 263.731 us; speedup vs baseline: 1.6831x; 1.0781x over previous
//
#include <hip/hip_runtime.h>
#include <hip/hip_bf16.h>

typedef __bf16 bf16x8 __attribute__((ext_vector_type(8)));
typedef float  f32x4  __attribute__((ext_vector_type(4)));

// float -> bf16 round-to-nearest-even (finite inputs)
__device__ __forceinline__ unsigned short f2bf(float f) {
    union { float f; unsigned int u; } v; v.f = f;
    unsigned int r = v.u + 0x7FFFu + ((v.u >> 16) & 1u);
    return (unsigned short)(r >> 16);
}

__device__ __forceinline__ void async16(const unsigned short* g, unsigned short* l) {
    __builtin_amdgcn_global_load_lds(
        (const __attribute__((address_space(1))) unsigned int*)g,
        (__attribute__((address_space(3))) unsigned int*)l,
        16, 0, 0);
}

// ---------------------------------------------------------------------------
// Transpose + cast: Xt[n][m] = (bf16) X[m][n]
// ---------------------------------------------------------------------------
__global__ __launch_bounds__(256) void transpose_to_bf16(
    const float* __restrict__ X, unsigned short* __restrict__ Xt, int Mr, int Nc)
{
    __shared__ float tile[32][33];
    const int bx = blockIdx.x * 32;
    const int by = blockIdx.y * 32;
    const int tx = threadIdx.x & 31;
    const int ty = threadIdx.x >> 5;
#pragma unroll
    for (int j = 0; j < 4; ++j)
        tile[ty + j * 8][tx] = X[(size_t)(by + ty + j * 8) * Nc + bx + tx];
    __syncthreads();
#pragma unroll
    for (int j = 0; j < 4; ++j)
        Xt[(size_t)(bx + ty + j * 8) * Mr + by + tx] = f2bf(tile[tx][ty + j * 8]);
}

// ---------------------------------------------------------------------------
// Generate transform matrix (bf16), exact integer angle reduction mod 4N.
// ---------------------------------------------------------------------------
__global__ __launch_bounds__(256) void gen_mat(
    unsigned short* __restrict__ out, int Nsz, int lg, int doSin)
{
    const int flat = (int)(((size_t)blockIdx.x * 256 + threadIdx.x) * 4);
    const int u  = flat >> lg;
    const int k0 = flat & (Nsz - 1);
    const unsigned int step = 2u * (unsigned int)u + 1u;
    const unsigned int mask = 4u * (unsigned int)Nsz - 1u;
    const float scale = 3.14159265358979323846f / (2.0f * (float)Nsz);
    unsigned short o[4];
#pragma unroll
    for (int j = 0; j < 4; ++j) {
        unsigned int p = ((unsigned int)(k0 + j) * step) & mask;
        float ang = (float)p * scale;
        float v = doSin ? __sinf(ang) : __cosf(ang);
        o[j] = f2bf(v);
    }
    uint2 pack;
    pack.x = (unsigned int)o[0] | ((unsigned int)o[1] << 16);
    pack.y = (unsigned int)o[2] | ((unsigned int)o[3] << 16);
    *reinterpret_cast<uint2*>(out + flat) = pack;
}

// ---------------------------------------------------------------------------
// 256x256 BT-layout bf16 GEMM, barrier-minimal pipelined tile:
//   C[i][j] = sum_k P[i][k] * Q[j][k]
// BK=64, 8 waves (2Mx4N), per-wave 128x64 C, LDS 128 KiB double-buffered.
// Per K-tile: only 2 barriers (mid: B-region WAR; end: buffer swap + vmcnt(4)).
// Compiler free to software-pipeline ds_reads under MFMAs (fine lgkmcnt).
// ---------------------------------------------------------------------------
__device__ __forceinline__ void store_out(float* C, size_t idx, float v) { C[idx] = v; }
__device__ __forceinline__ void store_out(unsigned short* C, size_t idx, float v) { C[idx] = f2bf(v); }

#define BARRIER __builtin_amdgcn_s_barrier()
#define PRIO1 __builtin_amdgcn_s_setprio(1)
#define PRIO0 __builtin_amdgcn_s_setprio(0)

// stage one half-tile slice: half h (0/1 = rows 0-127 / 128-255), L (0/1 = rows 0-63/64-127 of half)
#define STG_A(buf, h, L, kt) async16(pA + (size_t)((h) * 128 + (L) * 64) * K + (size_t)(kt) * 64, \
                                     ldsA + ((buf) << 14) + ((h) << 13) + ((L) << 12) + ldst)
#define STG_B(buf, h, L, kt) async16(pB + (size_t)((h) * 128 + (L) * 64) * K + (size_t)(kt) * 64, \
                                     ldsB + ((buf) << 14) + ((h) << 13) + ((L) << 12) + ldst)

#define LDA(buf, g) do { _Pragma("unroll") for (int mm = 0; mm < 4; ++mm) { \
    af[mm][0] = *(const bf16x8*)&ldsA[((buf) << 14) + aRow + ((g) * 4 + mm) * 1024 + sl0]; \
    af[mm][1] = *(const bf16x8*)&ldsA[((buf) << 14) + aRow + ((g) * 4 + mm) * 1024 + sl1]; } } while (0)

#define LDB(buf, p) do { _Pragma("unroll") for (int nn = 0; nn < 2; ++nn) { \
    bfr[(p) * 2 + nn][0] = *(const bf16x8*)&ldsB[((buf) << 14) + bRow + (((p) * 2 + nn)) * 1024 + sl0]; \
    bfr[(p) * 2 + nn][1] = *(const bf16x8*)&ldsB[((buf) << 14) + bRow + (((p) * 2 + nn)) * 1024 + sl1]; } } while (0)

#define MFMA_Q(g, p) do { _Pragma("unroll") for (int mm = 0; mm < 4; ++mm) \
    _Pragma("unroll") for (int nn = 0; nn < 2; ++nn) { \
    acc[(g) * 4 + mm][(p) * 2 + nn] = __builtin_amdgcn_mfma_f32_16x16x32_bf16( \
        af[mm][0], bfr[(p) * 2 + nn][0], acc[(g) * 4 + mm][(p) * 2 + nn], 0, 0, 0); \
    acc[(g) * 4 + mm][(p) * 2 + nn] = __builtin_amdgcn_mfma_f32_16x16x32_bf16( \
        af[mm][1], bfr[(p) * 2 + nn][1], acc[(g) * 4 + mm][(p) * 2 + nn], 0, 0, 0); } } while (0)

// One K-tile. buf = current, nbuf = other. Stages A(t+1)->nbuf (first half),
// B(t+2)->buf's B region (second half; dead after mid-barrier). vmN: 4 steady.
// Hazards enforced: (1) mid lgkmcnt(0)+barrier = all waves' B reads complete
// before STG_B overwrites; (2) end vmcnt(vmN)+barrier = next buf's data landed.
#define TILE(buf, nbuf, kt, doSA, doSB, vmN) do { \
    LDA(buf, 0); LDB(buf, 0); \
    if (doSA) { STG_A(nbuf, 0, 0, (kt) + 1); STG_A(nbuf, 0, 1, (kt) + 1); } \
    PRIO1; MFMA_Q(0, 0); PRIO0; \
    LDB(buf, 1); \
    if (doSA) { STG_A(nbuf, 1, 0, (kt) + 1); STG_A(nbuf, 1, 1, (kt) + 1); } \
    PRIO1; MFMA_Q(0, 1); PRIO0; \
    asm volatile("s_waitcnt lgkmcnt(0)" ::: "memory"); \
    BARRIER; \
    LDA(buf, 1); \
    if (doSB) { STG_B(buf, 0, 0, (kt) + 2); STG_B(buf, 0, 1, (kt) + 2); } \
    PRIO1; MFMA_Q(1, 0); PRIO0; \
    if (doSB) { STG_B(buf, 1, 0, (kt) + 2); STG_B(buf, 1, 1, (kt) + 2); } \
    PRIO1; MFMA_Q(1, 1); PRIO0; \
    asm volatile("s_waitcnt vmcnt(" #vmN ")" ::: "memory"); \
    BARRIER; } while (0)

template <typename OutT>
__global__ __launch_bounds__(512, 2) void gemm_bt8(
    const unsigned short* __restrict__ P,
    const unsigned short* __restrict__ Q,
    OutT* __restrict__ C,
    int Mr, int Nc, int K)
{
    __shared__ __align__(16) unsigned short ldsA[2 * 256 * 64];
    __shared__ __align__(16) unsigned short ldsB[2 * 256 * 64];

    const int tid  = threadIdx.x;
    const int lane = tid & 63;
    const int w    = tid >> 6;       // 0..7
    const int wm   = w >> 2;         // 0..1  (M half)
    const int wn   = w & 3;          // 0..3  (N quarter)

    // XCD-bijective block swizzle (gridDim.x % 8 == 0)
    const int nbx = Nc >> 8;
    const int bid = blockIdx.x;
    const int wg  = (bid & 7) * (gridDim.x >> 3) + (bid >> 3);
    const int brow = (wg / nbx) << 8;
    const int bcol = (wg % nbx) << 8;

    // staging constants: chunk c = L*512 + tid; row = c>>3 (within half), slot = c&7
    const int srow = tid >> 3;                        // 0..63 (L adds 64)
    const int slot = tid & 7;
    const int sxor = ((slot ^ (srow & 7)) << 3);      // pre-swizzled ushort col offset
    const unsigned short* pA = P + (size_t)(brow + srow) * K + sxor;
    const unsigned short* pB = Q + (size_t)(bcol + srow) * K + sxor;
    const int ldst = w << 9;                          // wave-uniform LDS dest (+lane*16B by HW)

    // fragment-read constants (read-side swizzle matches source-side XOR)
    const int lr = lane & 15, lk = lane >> 4, sx = lr & 7;
    const int sl0 = ((lk) ^ sx) << 3;                 // k-step 0 slot
    const int sl1 = ((4 + lk) ^ sx) << 3;             // k-step 1 slot
    const int aRow = (wm * 128 + lr) * 64;
    const int bRow = (wn * 64 + lr) * 64;

    bf16x8 af[4][2], bfr[4][2];
    f32x4 acc[8][4] = {};

    const int nt = K >> 6;   // K-tiles of 64

    // prologue: A(0),B(0) -> buf0; B(1) -> buf1. Keep B(1) in flight.
    STG_A(0, 0, 0, 0); STG_A(0, 0, 1, 0); STG_A(0, 1, 0, 0); STG_A(0, 1, 1, 0);
    STG_B(0, 0, 0, 0); STG_B(0, 0, 1, 0); STG_B(0, 1, 0, 0); STG_B(0, 1, 1, 0);
    STG_B(1, 0, 0, 1); STG_B(1, 0, 1, 1); STG_B(1, 1, 0, 1); STG_B(1, 1, 1, 1);
    asm volatile("s_waitcnt vmcnt(4)" ::: "memory");
    BARRIER;

    for (int i = 0; i < (nt >> 1) - 1; ++i) {
        const int t0 = 2 * i;
        TILE(0, 1, t0,     1, 1, 4);
        TILE(1, 0, t0 + 1, 1, 1, 4);
    }
    TILE(0, 1, nt - 2, 1, 0, 0);
    TILE(1, 0, nt - 1, 0, 0, 0);

    // epilogue: C/D layout col=lane&15, row=(lane>>4)*4+r
    const int r0 = brow + wm * 128 + (lane >> 4) * 4;
    const int c0 = bcol + wn * 64 + (lane & 15);
#pragma unroll
    for (int m = 0; m < 8; ++m)
#pragma unroll
        for (int n = 0; n < 4; ++n)
#pragma unroll
            for (int r = 0; r < 4; ++r)
                store_out(C, (size_t)(r0 + m * 16 + r) * Nc + (c0 + n * 16), acc[m][n][r]);
}

// ---------------------------------------------------------------------------
// launch: Y = A X B^T  via  Xt = X^T;  T = A (.) Xt;  Y = T (.) B
// ---------------------------------------------------------------------------
extern "C" void kernel_launch(void* const* d_in, const int* in_sizes, int n_in,
                              void* d_out, int out_size, void* d_ws, size_t ws_size,
                              hipStream_t stream) {
    const float* X = (const float*)d_in[0];
    const int Mr = in_sizes[1] / 2;   // 4096
    const int Nc = in_sizes[2] / 2;   // 4096
    const int lgM = 31 - __builtin_clz((unsigned)Mr);
    const int lgN = 31 - __builtin_clz((unsigned)Nc);

    unsigned short* Xt   = (unsigned short*)d_ws;              // [Nc][Mr]
    unsigned short* Wmat = Xt + (size_t)Nc * Mr;               // [4096][4096] (A then B)
    unsigned short* Tmat = Wmat + (size_t)Mr * Mr;             // [Mr][Nc]

    transpose_to_bf16<<<dim3(Nc / 32, Mr / 32), 256, 0, stream>>>(X, Xt, Mr, Nc);
    gen_mat<<<(Mr * Mr / 4) / 256, 256, 0, stream>>>(Wmat, Mr, lgM, 1);

    const int nblk = (Mr / 256) * (Nc / 256);
    gemm_bt8<unsigned short><<<nblk, 512, 0, stream>>>(Wmat, Xt, Tmat, Mr, Nc, Mr);

    gen_mat<<<(Nc * Nc / 4) / 256, 256, 0, stream>>>(Wmat, Nc, lgN, 0);
    gemm_bt8<float><<<nblk, 512, 0, stream>>>(Tmat, Wmat, (float*)d_out, Mr, Nc, Nc);
}